// Round 1
// baseline (2996.299 us; speedup 1.0000x reference)
//
#include <hip/hip_runtime.h>

#define B_TOT 4096
#define T_LEN 256
#define NCH   32

__device__ __forceinline__ float sigf(float x) { return 1.0f / (1.0f + expf(-x)); }

// ---------------- TCN: 3x (conv1d k=3 'same' + bias + ReLU) ----------------
// one block per batch row; activations live in LDS, transposed to [ch][t]
__global__ __launch_bounds__(256) void tcn_kernel(
    const float* __restrict__ x,    // [B][256][32]
    const float* __restrict__ cw1, const float* __restrict__ cb1,
    const float* __restrict__ cw2, const float* __restrict__ cb2,
    const float* __restrict__ cw3, const float* __restrict__ cb3,
    float* __restrict__ out)        // [B][256][32]
{
    __shared__ float bufA[NCH * 257];   // +1 pad breaks stride-256 bank conflicts
    __shared__ float bufB[NCH * 257];
    __shared__ float sW[NCH * 97];      // [o][i*3+k], 96->97 pad
    __shared__ float sB[NCH];

    const int b   = blockIdx.x;
    const int tid = threadIdx.x;
    const float* xb = x + (size_t)b * T_LEN * NCH;

    // load x[b] transposed: bufA[f][t] = x[b][t][f]   (global coalesced)
    #pragma unroll
    for (int c = 0; c < 32; ++c) {
        int idx = c * 256 + tid;
        int t = idx >> 5, f = idx & 31;
        bufA[f * 257 + t] = xb[idx];
    }
    __syncthreads();

    float* bin  = bufA;
    float* bout = bufB;
    const int o  = tid & 31;          // output channel
    const int t0 = (tid >> 5) * 32;   // this thread's t-tile start

    for (int layer = 0; layer < 3; ++layer) {
        const float* Wg = (layer == 0) ? cw1 : ((layer == 1) ? cw2 : cw3);
        const float* Bg = (layer == 0) ? cb1 : ((layer == 1) ? cb2 : cb3);
        for (int idx = tid; idx < 32 * 96; idx += 256) {
            int oo = idx / 96, rem = idx - oo * 96;
            sW[oo * 97 + rem] = Wg[idx];
        }
        if (tid < 32) sB[tid] = Bg[tid];
        __syncthreads();

        float acc[32];
        const float bias = sB[o];
        #pragma unroll
        for (int tt = 0; tt < 32; ++tt) acc[tt] = bias;

        for (int i = 0; i < 32; ++i) {
            const float w0 = sW[o * 97 + i * 3 + 0];
            const float w1 = sW[o * 97 + i * 3 + 1];
            const float w2 = sW[o * 97 + i * 3 + 2];
            const float* row = bin + i * 257;
            float vm = (t0 == 0) ? 0.0f : row[t0 - 1];
            float v0 = row[t0];
            #pragma unroll
            for (int tt = 0; tt < 32; ++tt) {
                float vp = (t0 + tt == 255) ? 0.0f : row[t0 + tt + 1];
                acc[tt] = fmaf(w0, vm, acc[tt]);
                acc[tt] = fmaf(w1, v0, acc[tt]);
                acc[tt] = fmaf(w2, vp, acc[tt]);
                vm = v0; v0 = vp;
            }
        }
        #pragma unroll
        for (int tt = 0; tt < 32; ++tt)
            bout[o * 257 + t0 + tt] = fmaxf(acc[tt], 0.0f);
        __syncthreads();
        float* tmp = bin; bin = bout; bout = tmp;
    }

    // write back un-transposed: out[b][t][f] = bin[f][t]
    float* og = out + (size_t)b * T_LEN * NCH;
    #pragma unroll
    for (int c = 0; c < 32; ++c) {
        int idx = c * 256 + tid;
        int t = idx >> 5, f = idx & 31;
        og[idx] = bin[f * 257 + t];
    }
}

// ---------------- recurrent scan: 1 batch row per wave ----------------
// lane l holds quantum amplitude l (6 qubits = 64 amps = 1 wave)
__global__ __launch_bounds__(256) void scan_kernel(
    const float* __restrict__ tcn,   // [B][256][32]
    const float* __restrict__ W_ih,  // [128][32]
    const float* __restrict__ W_hh,  // [128][32]
    const float* __restrict__ b_ih,  // [128]
    const float* __restrict__ b_hh,  // [128]
    const float* __restrict__ qw,    // [3][6]
    const float* __restrict__ Wq,    // [32][6]
    const float* __restrict__ bq,    // [32]
    const float* __restrict__ Wo,    // [1][32]
    const float* __restrict__ bo,    // [1]
    float* __restrict__ out)         // [B]
{
    __shared__ float sWih[128 * 33]; // [g][k], pad 32->33: conflict-free row reads
    __shared__ float sWhh[128 * 33];
    __shared__ float sxh[4][64];     // per wave: [0..31]=h, [32..63]=x_t

    const int tid = threadIdx.x;
    for (int idx = tid; idx < 128 * 32; idx += 256) {
        int g = idx >> 5, k = idx & 31;
        sWih[g * 33 + k] = W_ih[idx];
        sWhh[g * 33 + k] = W_hh[idx];
    }
    __syncthreads();

    const int w    = tid >> 6;
    const int lane = tid & 63;
    const int b    = blockIdx.x * 4 + w;
    const float* xrow = tcn + (size_t)b * T_LEN * NCH;
    float* xh = sxh[w];

    // per-lane gate biases: gates g=lane (i/f) and g=lane+64 (g/o)
    const float bias0 = b_ih[lane] + b_hh[lane];
    const float bias1 = b_ih[lane + 64] + b_hh[lane + 64];

    // variational-layer RY half-angle trig (constant over steps)
    float cw[18], sw[18];
    #pragma unroll
    for (int i = 0; i < 18; ++i) {
        float t = 0.5f * qw[i];
        sw[i] = sinf(t); cw[i] = cosf(t);
    }

    float wqr[6], bqr = 0.0f, wor = 0.0f;
    #pragma unroll
    for (int k = 0; k < 6; ++k) wqr[k] = 0.0f;
    if (lane < 32) {
        #pragma unroll
        for (int k = 0; k < 6; ++k) wqr[k] = Wq[lane * 6 + k];
        bqr = bq[lane];
        wor = Wo[lane];
    }

    float hh = 0.0f, cx = 0.0f;

    for (int t = 0; t < T_LEN; ++t) {
        if (lane < 32) {
            xh[lane]      = hh;                      // h from previous step
            xh[32 + lane] = xrow[t * 32 + lane];     // x_t
        }

        // gates: acc0 = gates[lane] (i|f), acc1 = gates[lane+64] (g|o)
        float acc0 = bias0, acc1 = bias1;
        #pragma unroll 8
        for (int k = 0; k < 32; ++k) {
            float xk = xh[32 + k], hk = xh[k];
            acc0 = fmaf(sWih[lane * 33 + k], xk, acc0);
            acc0 = fmaf(sWhh[lane * 33 + k], hk, acc0);
            acc1 = fmaf(sWih[(lane + 64) * 33 + k], xk, acc1);
            acc1 = fmaf(sWhh[(lane + 64) * 33 + k], hk, acc1);
        }
        float fg = __shfl_xor(acc0, 32, 64);   // lanes<32: f-gate
        float og = __shfl_xor(acc1, 32, 64);   // lanes<32: o-gate
        float c  = sigf(fg) * cx + sigf(acc0) * tanhf(acc1);
        float h  = sigf(og) * tanhf(c);
        h = 3.99f * h * (1.0f - h);            // logistic map
        float h0 = __shfl(h, 0, 64);
        float h1 = __shfl(h, 1, 64);
        if (lane == 0)      h = 1.0f - 1.4f * h0 * h0 + h1;  // henon
        else if (lane == 1) h = 0.3f * h0;
        cx = c;

        // ---- 6-qubit statevector sim, amplitude-per-lane ----
        float ca[6], sa[6];
        #pragma unroll
        for (int i = 0; i < 6; ++i) {
            float ang = 0.5f * __shfl(h, i, 64);
            sa[i] = sinf(ang); ca[i] = cosf(ang);
        }
        float re = (lane == 0) ? 1.0f : 0.0f;
        float im = 0.0f;

        // encoding: RX(a[i]), RY(a[i+1]), RZ(a[i+2]) on wire i
        #pragma unroll
        for (int i = 0; i < 6; ++i) {
            const int m = 32 >> i;
            const bool hi = (lane & m) != 0;
            { // RX: u01=u10=-i*s
                float pre = __shfl_xor(re, m, 64), pim = __shfl_xor(im, m, 64);
                float nr = ca[i] * re + sa[i] * pim;
                float ni = ca[i] * im - sa[i] * pre;
                re = nr; im = ni;
            }
            { // RY: partner coeff = hi ? +s : -s
                const int j = (i + 1) % 6;
                float pre = __shfl_xor(re, m, 64), pim = __shfl_xor(im, m, 64);
                float s_ = hi ? sa[j] : -sa[j];
                re = fmaf(s_, pre, ca[j] * re);
                im = fmaf(s_, pim, ca[j] * im);
            }
            { // RZ: diag e^{∓i t/2}
                const int j = (i + 2) % 6;
                float s_ = hi ? -sa[j] : sa[j];
                float nr = ca[j] * re + s_ * im;
                float ni = ca[j] * im - s_ * re;
                re = nr; im = ni;
            }
        }
        // 3 variational layers: 6x RY(weights) then ring CNOTs
        #pragma unroll
        for (int l = 0; l < 3; ++l) {
            #pragma unroll
            for (int q = 0; q < 6; ++q) {
                const int m = 32 >> q;
                const bool hi = (lane & m) != 0;
                float pre = __shfl_xor(re, m, 64), pim = __shfl_xor(im, m, 64);
                float s_ = hi ? sw[l * 6 + q] : -sw[l * 6 + q];
                re = fmaf(s_, pre, cw[l * 6 + q] * re);
                im = fmaf(s_, pim, cw[l * 6 + q] * im);
            }
            #pragma unroll
            for (int q = 0; q < 6; ++q) {
                const int mc = 32 >> q;
                const int mt = 32 >> ((q + 1) % 6);
                float pre = __shfl_xor(re, mt, 64), pim = __shfl_xor(im, mt, 64);
                const bool ctrl = (lane & mc) != 0;
                re = ctrl ? pre : re;
                im = ctrl ? pim : im;
            }
        }
        // probs -> all 6 <Z_i> via one Walsh-Hadamard butterfly
        float p = re * re + im * im;
        #pragma unroll
        for (int st = 0; st < 6; ++st) {
            const int m = 1 << st;
            float pp = __shfl_xor(p, m, 64);
            p = (lane & m) ? (pp - p) : (p + pp);
        }
        float qv[6];
        #pragma unroll
        for (int k = 0; k < 6; ++k) qv[k] = __shfl(p, 32 >> k, 64); // e_i at lane 2^(5-i)

        // hh += q @ Wq.T + bq
        float upd = bqr;
        #pragma unroll
        for (int k = 0; k < 6; ++k) upd = fmaf(qv[k], wqr[k], upd);
        hh = h + upd;
    }

    // out[b] = sigmoid(hx . Wo + bo)
    float contrib = (lane < 32) ? hh * wor : 0.0f;
    #pragma unroll
    for (int off = 32; off >= 1; off >>= 1)
        contrib += __shfl_xor(contrib, off, 64);
    if (lane == 0) out[b] = sigf(contrib + bo[0]);
}

extern "C" void kernel_launch(void* const* d_in, const int* in_sizes, int n_in,
                              void* d_out, int out_size, void* d_ws, size_t ws_size,
                              hipStream_t stream)
{
    const float* x    = (const float*)d_in[0];
    const float* cw1  = (const float*)d_in[1];
    const float* cb1  = (const float*)d_in[2];
    const float* cw2  = (const float*)d_in[3];
    const float* cb2  = (const float*)d_in[4];
    const float* cw3  = (const float*)d_in[5];
    const float* cb3  = (const float*)d_in[6];
    const float* W_ih = (const float*)d_in[7];
    const float* W_hh = (const float*)d_in[8];
    const float* b_ih = (const float*)d_in[9];
    const float* b_hh = (const float*)d_in[10];
    const float* qw   = (const float*)d_in[11];
    const float* Wq   = (const float*)d_in[12];
    const float* bq   = (const float*)d_in[13];
    const float* Wo   = (const float*)d_in[14];
    const float* bo   = (const float*)d_in[15];

    float* tcn = (float*)d_ws;  // [4096][256][32] f32 = 128 MiB scratch

    hipLaunchKernelGGL(tcn_kernel, dim3(B_TOT), dim3(256), 0, stream,
                       x, cw1, cb1, cw2, cb2, cw3, cb3, tcn);
    hipLaunchKernelGGL(scan_kernel, dim3(B_TOT / 4), dim3(256), 0, stream,
                       tcn, W_ih, W_hh, b_ih, b_hh, qw, Wq, bq, Wo, bo,
                       (float*)d_out);
}